// Round 15
// baseline (721.029 us; speedup 1.0000x reference)
//
#include <hip/hip_runtime.h>

// DecoderGRU: h_{t+1} = GRUCell(h_t, h_t), 64 steps. Combined gates: r,z use
// (W_ih+W_hh); n keeps i_n,h_n -> one [512,1024]x[1024,4096] bf16 GEMM + fused
// GRU update per step.
// R15: persistent kernel v7 -- wave-role split. After the G-write barrier,
// kh=0 waves (tid<256) run the epilogue (G read, GRU, Anext store+drain,
// flag release via LDS counter, out stores) WHILE kh=1 waves poll next-step
// flags and stage chunks 0-3 of slot t+1 into LDS 0-64K (G lives in the
// upper 64K: [8][64][32] f32, XOR-swizzled). One barrier later all waves
// stage chunks 4-7 and start MFMA 0-3 with no wait. 4 barriers/step.
// Rot A slots + sc1 producer stores + parallel flags + B in regs: R11-R14
// proven, unchanged.

typedef float  f32x4 __attribute__((ext_vector_type(4)));
typedef __bf16 bf16x8 __attribute__((ext_vector_type(8)));
typedef unsigned short u16x8 __attribute__((ext_vector_type(8)));
typedef unsigned long long u64x2 __attribute__((ext_vector_type(2)));

#define GPTR(p) ((const __attribute__((address_space(1))) unsigned int*)(p))
#define LPTR(p) ((__attribute__((address_space(3))) unsigned int*)(p))

// ws layout
#define WB_OFF   0u            // 8 MB frag-packed bf16 weights
#define BIAS_OFF 8388608u      // 16 KB combined biases [4][1024]
#define FLAG_OFF 8404992u      // 64 KB flags [64 t][8 rb][32 j]
#define AROT_OFF 8470528u      // 65 x 1 MB A slots (rot) / 2 x 1 MB (pp)
#define WS_NEED_ROT (8470528ull + 65ull * 1048576ull)

__device__ __forceinline__ unsigned short f2bf(float f){
  unsigned int u = __builtin_bit_cast(unsigned int, f);
  u = (u + 0x7FFFu + ((u >> 16) & 1u)) >> 16;
  return (unsigned short)u;
}

// ---------------------------------------------------------------------------
// B layout: byte = j*262144 + c*32768 + fb*1024 + lane*16 + (k&7)*2,
//   j=col>>5, c=k>>7, fb=(((k>>5)&3)*4+g)*2+((col>>4)&1),
//   lane=(col&15)+((k>>3)&3)*16.  gates: 0=r(+) 1=z(+) 2=i_n(ih) 3=h_n(hh)
// ---------------------------------------------------------------------------
extern "C" __global__ void gru_weights(const float* __restrict__ wih,
                                       const float* __restrict__ whh,
                                       char* __restrict__ WB){
  int gt  = blockIdx.x * 256 + threadIdx.x;   // 524288 threads
  int k0  = (gt & 127) << 3;                  // 8 k's per thread
  int gid = gt >> 7;
  int g   = gid >> 10, colg = gid & 1023;
  int srow = (g < 2) ? g * 1024 + colg : 2048 + colg;
  const float* pa = ((g == 3) ? whh : wih) + srow * 1024 + k0;
  f32x4 v0 = ((const f32x4*)pa)[0];
  f32x4 v1 = ((const f32x4*)pa)[1];
  if (g < 2){
    const float* pb = whh + srow * 1024 + k0;
    v0 += ((const f32x4*)pb)[0];
    v1 += ((const f32x4*)pb)[1];
  }
  u16x8 o;
  #pragma unroll
  for (int e = 0; e < 4; e++){ o[e] = f2bf(v0[e]); o[4 + e] = f2bf(v1[e]); }
  int cck = k0 >> 7;
  int fb  = (((k0 >> 5) & 3) * 4 + g) * 2 + ((colg >> 4) & 1);
  int lane= (colg & 15) + ((k0 >> 3) & 3) * 16;
  int addr= (colg >> 5) * 262144 + cck * 32768 + fb * 1024 + lane * 16;
  *(u16x8*)(WB + addr) = o;
}

// ---------------------------------------------------------------------------
// A layout (64-row slabs): byte = (row>>6)*131072 + (hk>>7)*16384
//   + (((hk>>5)&3)*4 + ((row&63)>>4))*1024
//   + ((row&15)+((hk>>3)&3)*16)*16 + (hk&7)*2
// ---------------------------------------------------------------------------
extern "C" __global__ void gru_init(const float* __restrict__ hidden,
                                    const float* __restrict__ bih,
                                    const float* __restrict__ bhh,
                                    char* __restrict__ A0,
                                    float* __restrict__ bias,
                                    int* __restrict__ flag){
  int gt = blockIdx.x * 256 + threadIdx.x;    // 65536 threads, 8 elems each
  int e0 = gt * 8;
  int r  = e0 >> 10, c0 = e0 & 1023;
  f32x4 v0 = ((const f32x4*)(hidden + e0))[0];
  f32x4 v1 = ((const f32x4*)(hidden + e0))[1];
  u16x8 o;
  #pragma unroll
  for (int e = 0; e < 4; e++){ o[e] = f2bf(v0[e]); o[4 + e] = f2bf(v1[e]); }
  int addr = (r >> 6) * 131072 + (c0 >> 7) * 16384
           + (((c0 >> 5) & 3) * 4 + ((r & 63) >> 4)) * 1024
           + ((r & 15) + ((c0 >> 3) & 3) * 16) * 16;
  *(u16x8*)(A0 + addr) = o;
  if (blockIdx.x < 16){
    int bi = blockIdx.x * 256 + threadIdx.x;  // 4096 bias entries
    int g = bi >> 10, c = bi & 1023;
    float v = (g == 0) ? bih[c]        + bhh[c]
            : (g == 1) ? bih[1024 + c] + bhh[1024 + c]
            : (g == 2) ? bih[2048 + c] : bhh[2048 + c];
    bias[bi] = v;
  }
  if (gt < 16384) flag[gt] = 0;               // 64 KB flag region
}

// ---------------------------------------------------------------------------
// Persistent body. rb=bid&7, j=bid>>3. Wave wv: g=wv&3, kh=wv>>2.
// LDS: A 8-chunk ring (8x16KB); G [8][64][32] f32 (XOR-swizzled) overlays the
// UPPER 64KB (chunks 4-7) during the epilogue phase.
// Per step: MFMA 0-3 (no wait) -> vmcnt(0)+bar -> MFMA 4-7 -> bar ->
// G write -> bar -> {kh=0: epilogue+flag || kh=1: poll+stage 0-3} -> bar ->
// all: stage 4-7 -> loop.
// ---------------------------------------------------------------------------
template<bool ROT>
__device__ __forceinline__ void gru_seq_body(
    char* __restrict__ Arot, const char* __restrict__ WB,
    const float* __restrict__ bias, const float* __restrict__ hidden,
    float* __restrict__ out, int* __restrict__ flag)
{
  __shared__ __align__(16) char lds[131072];
  __shared__ int epi_cnt;
  const int tid = threadIdx.x;
  const int wv = tid >> 6, ln = tid & 63;
  const int g = wv & 3, kh = wv >> 2;
  const int lrow = ln & 15, lq = ln >> 4;
  const int bid = blockIdx.x;
  const int rb = bid & 7, j = bid >> 3;
  const int abase = rb * 131072;
  const int bbase = j * 262144;
  const int AUX = ROT ? 0 : 17;   // rot: cached reads; pp: sc1 bypass

  if (tid == 0) epi_cnt = 0;

  // ---- B into registers ONCE for all 64 steps ----
  f32x4 braw[16][2];
  #pragma unroll
  for (int c = 0; c < 8; c++)
    #pragma unroll
    for (int p = 0; p < 2; p++)
      #pragma unroll
      for (int n = 0; n < 2; n++){
        braw[c * 2 + p][n] = *(const f32x4*)(WB + bbase + c * 32768
                               + (((kh * 2 + p) * 4 + g) * 2 + n) * 1024 + ln * 16);
        asm volatile("" : "+v"(braw[c * 2 + p][n]));
      }

  // ---- kh=0 epilogue geometry (valid for tid<256) ----
  const int erow = tid >> 2, ec0 = (tid & 3) * 8;     // 64 rows x 4 col-octets
  const int grow = rb * 64 + erow, gcol = j * 32 + ec0;
  const int aaddr = rb * 131072 + (gcol >> 7) * 16384
                  + (((gcol >> 5) & 3) * 4 + (erow >> 4)) * 1024
                  + ((erow & 15) + ((gcol >> 3) & 3) * 16) * 16;
  float* Gf = (float*)(lds + 65536);                  // [8][64][32] swizzled
  const int q = wv;                                   // kh*4+g

#define STAGE03(bp) do { \
    const int w2 = wv - 4; \
    _Pragma("unroll") \
    for (int i = 0; i < 16; i++) \
      __builtin_amdgcn_global_load_lds( \
          GPTR((bp) + abase + w2 * 16384 + i * 1024 + ln * 16), \
          LPTR(lds + w2 * 16384 + i * 1024 + ln * 16), 16, 0, AUX); \
  } while (0)

#define STAGE47(bp) do { \
    _Pragma("unroll") \
    for (int i = 0; i < 8; i++) \
      __builtin_amdgcn_global_load_lds( \
          GPTR((bp) + abase + 65536 + wv * 8192 + i * 1024 + ln * 16), \
          LPTR(lds + 65536 + wv * 8192 + i * 1024 + ln * 16), 16, 0, AUX); \
  } while (0)

#define CHUNK_NB(c) do { \
    _Pragma("unroll") \
    for (int p = 0; p < 2; p++){ \
      const int ks = kh * 2 + p; \
      bf16x8 a[4]; \
      _Pragma("unroll") \
      for (int m = 0; m < 4; m++) \
        a[m] = *(const bf16x8*)(lds + (c) * 16384 + (ks * 4 + m) * 1024 + ln * 16); \
      _Pragma("unroll") \
      for (int m = 0; m < 4; m++) \
        _Pragma("unroll") \
        for (int n = 0; n < 2; n++) \
          acc[m][n] = __builtin_amdgcn_mfma_f32_16x16x32_bf16( \
              a[m], __builtin_bit_cast(bf16x8, braw[(c) * 2 + p][n]), acc[m][n], 0, 0, 0); \
    } \
  } while (0)

  // ---- prologue: stage slot 0 (written by gru_init; kernel-boundary coherent)
  if (kh == 1){
    STAGE03(Arot);
    asm volatile("s_waitcnt vmcnt(0)" ::: "memory");
  }
  __syncthreads();
  STAGE47(Arot);

  #pragma unroll 1
  for (int t = 0; t < 64; t++){
    char* Anxt = Arot + (size_t)(ROT ? (t + 1) : ((t + 1) & 1)) * 1048576u;

    f32x4 acc[4][2];
    #pragma unroll
    for (int m = 0; m < 4; m++)
      #pragma unroll
      for (int n = 0; n < 2; n++) acc[m][n] = f32x4{0.f,0.f,0.f,0.f};

    // MFMA 0-3: chunks already resident (staged + drained before last barrier)
    __builtin_amdgcn_s_setprio(1);
    CHUNK_NB(0); CHUNK_NB(1); CHUNK_NB(2); CHUNK_NB(3);
    __builtin_amdgcn_s_setprio(0);

    // chunks 4-7 resident after drain + barrier
    asm volatile("s_waitcnt vmcnt(0)" ::: "memory");
    __syncthreads();
    __builtin_amdgcn_s_setprio(1);
    CHUNK_NB(4); CHUNK_NB(5); CHUNK_NB(6); CHUNK_NB(7);
    __builtin_amdgcn_s_setprio(0);
    __syncthreads();                          // (a) LDS 64-128K now free for G

    // ---- G write: [8][64][32] f32, col ^= (row&7)<<2 ----
    #pragma unroll
    for (int m = 0; m < 4; m++)
      #pragma unroll
      for (int r4 = 0; r4 < 4; r4++){
        int row = m * 16 + lq * 4 + r4;
        int sw = (row & 7) << 2;
        Gf[q * 2048 + row * 32 + (lrow ^ sw)]          = acc[m][0][r4];
        Gf[q * 2048 + row * 32 + ((16 + lrow) ^ sw)]   = acc[m][1][r4];
      }
    __syncthreads();                          // (b)

    if (tid < 256){
      // ================= kh=0: epilogue =================
      const int sw = (erow & 7) << 2;
      const float* Gr = Gf + erow * 32;
      const int cA = ec0 ^ sw, cB = (ec0 + 4) ^ sw;
      f32x4 v0[4], v1[4];
      #pragma unroll
      for (int g2 = 0; g2 < 4; g2++){
        v0[g2] = *(const f32x4*)(Gr + g2 * 2048 + cA)
               + *(const f32x4*)(Gr + (g2 + 4) * 2048 + cA)
               + *(const f32x4*)(bias + g2 * 1024 + gcol);
        v1[g2] = *(const f32x4*)(Gr + g2 * 2048 + cB)
               + *(const f32x4*)(Gr + (g2 + 4) * 2048 + cB)
               + *(const f32x4*)(bias + g2 * 1024 + gcol + 4);
      }
      const float* hp = (t == 0) ? (hidden + grow * 1024 + gcol)
                                 : (out + (size_t)grow * 65536 + (size_t)(t - 1) * 1024 + gcol);
      f32x4 h0 = ((const f32x4*)hp)[0], h1 = ((const f32x4*)hp)[1];
      f32x4 o0, o1; u16x8 hb;
      #pragma unroll
      for (int hv = 0; hv < 2; hv++){
        f32x4 vr = hv ? v1[0] : v0[0], vz = hv ? v1[1] : v0[1];
        f32x4 vi = hv ? v1[2] : v0[2], vh = hv ? v1[3] : v0[3];
        f32x4 ho = hv ? h1 : h0, vout;
        #pragma unroll
        for (int e = 0; e < 4; e++){
          float rr = 1.f / (1.f + __expf(-vr[e]));
          float zz = 1.f / (1.f + __expf(-vz[e]));
          float x  = vi[e] + rr * vh[e];
          float ex = __expf(-2.f * x);
          float nn = (1.f - ex) / (1.f + ex);
          float hn = nn + zz * (ho[e] - nn);
          vout[e] = hn;
          hb[hv * 4 + e] = f2bf(hn);
        }
        if (hv) o1 = vout; else o0 = vout;
      }
      // Anext (sc1 write-through) -> drain -> count -> flag; out stores after.
      u64x2 hw = __builtin_bit_cast(u64x2, hb);
      __hip_atomic_store((unsigned long long*)(Anxt + aaddr),     hw[0],
                         __ATOMIC_RELAXED, __HIP_MEMORY_SCOPE_SYSTEM);
      __hip_atomic_store((unsigned long long*)(Anxt + aaddr + 8), hw[1],
                         __ATOMIC_RELAXED, __HIP_MEMORY_SCOPE_SYSTEM);
      asm volatile("s_waitcnt vmcnt(0)" ::: "memory");
      if ((tid & 63) == 0){
        int old = __hip_atomic_fetch_add(&epi_cnt, 1,
                      __ATOMIC_RELAXED, __HIP_MEMORY_SCOPE_WORKGROUP);
        if ((old & 3) == 3)
          __hip_atomic_store(&flag[(t * 8 + rb) * 32 + j], 1,
                             __ATOMIC_RELAXED, __HIP_MEMORY_SCOPE_SYSTEM);
      }
      float* op = out + (size_t)grow * 65536 + (size_t)t * 1024 + gcol;
      ((f32x4*)op)[0] = o0;
      ((f32x4*)op)[1] = o1;
    } else if (t < 63){
      // ================= kh=1: poll + stage chunks 0-3 of slot t+1 =========
      const int* fp = flag + (t * 8 + rb) * 32 + (ln & 31);
      for (;;){
        int v = __hip_atomic_load(fp, __ATOMIC_RELAXED, __HIP_MEMORY_SCOPE_SYSTEM);
        if (__all(v != 0)) break;
        __builtin_amdgcn_s_sleep(1);
      }
      STAGE03(Anxt);
      asm volatile("s_waitcnt vmcnt(0)" ::: "memory");
    }
    __syncthreads();                          // (c)
    if (t < 63)
      STAGE47(Anxt);                          // hides under next MFMA 0-3
  }
#undef STAGE03
#undef STAGE47
#undef CHUNK_NB
}

extern "C" __global__ void __launch_bounds__(512, 1)
gru_seq_rot(char* Arot, const char* WB, const float* bias,
            const float* hidden, float* out, int* flag){
  gru_seq_body<true>(Arot, WB, bias, hidden, out, flag);
}

extern "C" __global__ void __launch_bounds__(512, 1)
gru_seq_pp(char* Arot, const char* WB, const float* bias,
           const float* hidden, float* out, int* flag){
  gru_seq_body<false>(Arot, WB, bias, hidden, out, flag);
}

// ---------------------------------------------------------------------------
extern "C" void kernel_launch(void* const* d_in, const int* in_sizes, int n_in,
                              void* d_out, int out_size, void* d_ws, size_t ws_size,
                              hipStream_t stream){
  const float* hidden = (const float*)d_in[0];
  const float* wih    = (const float*)d_in[1];
  const float* whh    = (const float*)d_in[2];
  const float* bih    = (const float*)d_in[3];
  const float* bhh    = (const float*)d_in[4];
  char*  ws   = (char*)d_ws;
  char*  WB   = ws + WB_OFF;
  float* bias = (float*)(ws + BIAS_OFF);
  int*   flag = (int*)(ws + FLAG_OFF);
  char*  Arot = ws + AROT_OFF;
  float* out  = (float*)d_out;

  hipLaunchKernelGGL(gru_weights, dim3(2048), dim3(256), 0, stream, wih, whh, WB);
  hipLaunchKernelGGL(gru_init,    dim3(256),  dim3(256), 0, stream,
                     hidden, bih, bhh, Arot, bias, flag);
  if (ws_size >= WS_NEED_ROT)
    hipLaunchKernelGGL(gru_seq_rot, dim3(256), dim3(512), 0, stream,
                       Arot, (const char*)WB, (const float*)bias,
                       hidden, out, flag);
  else
    hipLaunchKernelGGL(gru_seq_pp,  dim3(256), dim3(512), 0, stream,
                       Arot, (const char*)WB, (const float*)bias,
                       hidden, out, flag);
}

// Round 16
// 687.904 us; speedup vs baseline: 1.0482x; 1.0482x over previous
//
#include <hip/hip_runtime.h>

// DecoderGRU: h_{t+1} = GRUCell(h_t, h_t), 64 steps. Combined gates: r,z use
// (W_ih+W_hh); n keeps i_n,h_n -> one [512,1024]x[1024,4096] bf16 GEMM + fused
// GRU update per step.
// R16: persistent kernel v8 -- chunk-granular self-timed dataflow. Chunk c of
// the rb A-slab is produced by blocks j=4c..4c+3 only. Wave w owns chunk w:
// polls its 4 producer flag words, stages 16KB, vmcnt(0), publishes
// ready[w]=t+2 (LDS release). Consumers gate each chunk's MFMA on an LDS
// acquire spin (no K-loop barriers; skew absorbed per-chunk: max-of-4
// pipelined instead of max-of-32 rendezvous). Poll+stage overlap the GRU
// epilogue. 3 barriers/step (G-exchange fencing only). h in regs; B in regs;
// rot A slots; sc1 producer stores -- all R11-R14 proven.

typedef float  f32x4 __attribute__((ext_vector_type(4)));
typedef __bf16 bf16x8 __attribute__((ext_vector_type(8)));
typedef unsigned short u16x8 __attribute__((ext_vector_type(8)));
typedef unsigned short u16x4 __attribute__((ext_vector_type(4)));

#define GPTR(p) ((const __attribute__((address_space(1))) unsigned int*)(p))
#define LPTR(p) ((__attribute__((address_space(3))) unsigned int*)(p))

// ws layout
#define WB_OFF   0u            // 8 MB frag-packed bf16 weights
#define BIAS_OFF 8388608u      // 16 KB combined biases [4][1024]
#define FLAG_OFF 8404992u      // 64 KB flags [64 t][8 rb][32 j]
#define AROT_OFF 8470528u      // 65 x 1 MB A slots (rot) / 2 x 1 MB (pp)
#define WS_NEED_ROT (8470528ull + 65ull * 1048576ull)

__device__ __forceinline__ unsigned short f2bf(float f){
  unsigned int u = __builtin_bit_cast(unsigned int, f);
  u = (u + 0x7FFFu + ((u >> 16) & 1u)) >> 16;
  return (unsigned short)u;
}

// ---------------------------------------------------------------------------
// B layout: byte = j*262144 + c*32768 + fb*1024 + lane*16 + (k&7)*2,
//   j=col>>5, c=k>>7, fb=(((k>>5)&3)*4+g)*2+((col>>4)&1),
//   lane=(col&15)+((k>>3)&3)*16.  gates: 0=r(+) 1=z(+) 2=i_n(ih) 3=h_n(hh)
// ---------------------------------------------------------------------------
extern "C" __global__ void gru_weights(const float* __restrict__ wih,
                                       const float* __restrict__ whh,
                                       char* __restrict__ WB){
  int gt  = blockIdx.x * 256 + threadIdx.x;   // 524288 threads
  int k0  = (gt & 127) << 3;                  // 8 k's per thread
  int gid = gt >> 7;
  int g   = gid >> 10, colg = gid & 1023;
  int srow = (g < 2) ? g * 1024 + colg : 2048 + colg;
  const float* pa = ((g == 3) ? whh : wih) + srow * 1024 + k0;
  f32x4 v0 = ((const f32x4*)pa)[0];
  f32x4 v1 = ((const f32x4*)pa)[1];
  if (g < 2){
    const float* pb = whh + srow * 1024 + k0;
    v0 += ((const f32x4*)pb)[0];
    v1 += ((const f32x4*)pb)[1];
  }
  u16x8 o;
  #pragma unroll
  for (int e = 0; e < 4; e++){ o[e] = f2bf(v0[e]); o[4 + e] = f2bf(v1[e]); }
  int cck = k0 >> 7;
  int fb  = (((k0 >> 5) & 3) * 4 + g) * 2 + ((colg >> 4) & 1);
  int lane= (colg & 15) + ((k0 >> 3) & 3) * 16;
  int addr= (colg >> 5) * 262144 + cck * 32768 + fb * 1024 + lane * 16;
  *(u16x8*)(WB + addr) = o;
}

// ---------------------------------------------------------------------------
// A layout (64-row slabs): byte = (row>>6)*131072 + (hk>>7)*16384
//   + (((hk>>5)&3)*4 + ((row&63)>>4))*1024
//   + ((row&15)+((hk>>3)&3)*16)*16 + (hk&7)*2
// ---------------------------------------------------------------------------
extern "C" __global__ void gru_init(const float* __restrict__ hidden,
                                    const float* __restrict__ bih,
                                    const float* __restrict__ bhh,
                                    char* __restrict__ A0,
                                    float* __restrict__ bias,
                                    int* __restrict__ flag){
  int gt = blockIdx.x * 256 + threadIdx.x;    // 65536 threads, 8 elems each
  int e0 = gt * 8;
  int r  = e0 >> 10, c0 = e0 & 1023;
  f32x4 v0 = ((const f32x4*)(hidden + e0))[0];
  f32x4 v1 = ((const f32x4*)(hidden + e0))[1];
  u16x8 o;
  #pragma unroll
  for (int e = 0; e < 4; e++){ o[e] = f2bf(v0[e]); o[4 + e] = f2bf(v1[e]); }
  int addr = (r >> 6) * 131072 + (c0 >> 7) * 16384
           + (((c0 >> 5) & 3) * 4 + ((r & 63) >> 4)) * 1024
           + ((r & 15) + ((c0 >> 3) & 3) * 16) * 16;
  *(u16x8*)(A0 + addr) = o;
  if (blockIdx.x < 16){
    int bi = blockIdx.x * 256 + threadIdx.x;  // 4096 bias entries
    int g = bi >> 10, c = bi & 1023;
    float v = (g == 0) ? bih[c]        + bhh[c]
            : (g == 1) ? bih[1024 + c] + bhh[1024 + c]
            : (g == 2) ? bih[2048 + c] : bhh[2048 + c];
    bias[bi] = v;
  }
  if (gt < 16384) flag[gt] = 0;               // 64 KB flag region
}

// ---------------------------------------------------------------------------
// Persistent body. rb=bid&7, j=bid>>3. Wave wv: g=wv&3, kh=wv>>2; wave wv
// also owns LDS chunk wv (stage + ready handshake).
// LDS: A 8-chunk ring (8x16KB); G [8][64][34] f32 overlays @0 post-K-loop;
// ready[8] + epi_cnt in separate shared ints.
// Per step: {spin ready[c]>=t+1; 16 MFMA} x8 (no barriers) -> bar -> G write
// -> bar -> G read -> bar -> GRU + Anext/out stores + vmcnt + epi count
// (8th wave releases block flag) -> poll own 4 producers -> stage chunk wv
// of slot t+1 -> vmcnt(0) -> ready[wv]=t+2.
// ---------------------------------------------------------------------------
template<bool ROT>
__device__ __forceinline__ void gru_seq_body(
    char* __restrict__ Arot, const char* __restrict__ WB,
    const float* __restrict__ bias, const float* __restrict__ hidden,
    float* __restrict__ out, int* __restrict__ flag)
{
  __shared__ __align__(16) char lds[131072];
  __shared__ int ready[8];
  __shared__ int epi_cnt;
  const int tid = threadIdx.x;
  const int wv = tid >> 6, ln = tid & 63;
  const int g = wv & 3, kh = wv >> 2;
  const int lrow = ln & 15, lq = ln >> 4;
  const int bid = blockIdx.x;
  const int rb = bid & 7, j = bid >> 3;
  const int abase = rb * 131072;
  const int bbase = j * 262144;
  const int AUX = ROT ? 0 : 17;   // rot: cached reads; pp: sc1 bypass

  if (tid < 8) ready[tid] = 0;
  if (tid == 0) epi_cnt = 0;

  // ---- B into registers ONCE for all 64 steps ----
  f32x4 braw[16][2];
  #pragma unroll
  for (int c = 0; c < 8; c++)
    #pragma unroll
    for (int p = 0; p < 2; p++)
      #pragma unroll
      for (int n = 0; n < 2; n++){
        braw[c * 2 + p][n] = *(const f32x4*)(WB + bbase + c * 32768
                               + (((kh * 2 + p) * 4 + g) * 2 + n) * 1024 + ln * 16);
        asm volatile("" : "+v"(braw[c * 2 + p][n]));
      }

  // ---- per-thread epilogue geometry; h and biases in regs ----
  const int erow = tid >> 3, ec0 = (tid & 7) * 4;
  const int grow = rb * 64 + erow, gcol = j * 32 + ec0;
  const f32x4 bR = *(const f32x4*)(bias + gcol);
  const f32x4 bZ = *(const f32x4*)(bias + 1024 + gcol);
  const f32x4 bI = *(const f32x4*)(bias + 2048 + gcol);
  const f32x4 bH = *(const f32x4*)(bias + 3072 + gcol);
  f32x4 h = *(const f32x4*)(hidden + grow * 1024 + gcol);
  const int aaddr = rb * 131072 + (j >> 2) * 16384
                  + ((j & 3) * 4 + (erow >> 4)) * 1024
                  + ((erow & 15) + ((ec0 >> 3) & 3) * 16) * 16 + (ec0 & 7) * 2;
  float* G = (float*)lds;                      // overlays A-ring post-K-loop
  const int q = kh * 4 + g;

// wave wv stages ITS chunk (16KB = 16 x 1KB wave-instructions)
#define STAGE_W(bp) do { \
    _Pragma("unroll") \
    for (int i = 0; i < 16; i++) \
      __builtin_amdgcn_global_load_lds( \
          GPTR((bp) + abase + wv * 16384 + i * 1024 + ln * 16), \
          LPTR(lds + wv * 16384 + i * 1024 + ln * 16), 16, 0, AUX); \
  } while (0)

#define CHUNK_NB(c) do { \
    _Pragma("unroll") \
    for (int p = 0; p < 2; p++){ \
      const int ks = kh * 2 + p; \
      bf16x8 a[4]; \
      _Pragma("unroll") \
      for (int m = 0; m < 4; m++) \
        a[m] = *(const bf16x8*)(lds + (c) * 16384 + (ks * 4 + m) * 1024 + ln * 16); \
      _Pragma("unroll") \
      for (int m = 0; m < 4; m++) \
        _Pragma("unroll") \
        for (int n = 0; n < 2; n++) \
          acc[m][n] = __builtin_amdgcn_mfma_f32_16x16x32_bf16( \
              a[m], __builtin_bit_cast(bf16x8, braw[(c) * 2 + p][n]), acc[m][n], 0, 0, 0); \
    } \
  } while (0)

// acquire-spin on LDS ready word, then pin instruction order (rule #18)
#define WAITCHUNK(c, tgt) do { \
    while (__hip_atomic_load(&ready[c], __ATOMIC_ACQUIRE, \
                             __HIP_MEMORY_SCOPE_WORKGROUP) < (tgt)) \
      __builtin_amdgcn_s_sleep(1); \
    __builtin_amdgcn_sched_barrier(0); \
  } while (0)

  // ---- prologue: every wave stages its chunk of slot 0, publishes ready=1
  __syncthreads();                 // ready[]/epi_cnt zero-init visible
  STAGE_W(Arot);
  asm volatile("s_waitcnt vmcnt(0)" ::: "memory");
  __hip_atomic_store(&ready[wv], 1, __ATOMIC_RELEASE, __HIP_MEMORY_SCOPE_WORKGROUP);

  #pragma unroll 1
  for (int t = 0; t < 64; t++){
    char* Anxt = Arot + (size_t)(ROT ? (t + 1) : ((t + 1) & 1)) * 1048576u;

    f32x4 acc[4][2];
    #pragma unroll
    for (int m = 0; m < 4; m++)
      #pragma unroll
      for (int n = 0; n < 2; n++) acc[m][n] = f32x4{0.f,0.f,0.f,0.f};

    // ---- self-timed K-loop: no block barriers ----
    __builtin_amdgcn_s_setprio(1);
    WAITCHUNK(0, t + 1); CHUNK_NB(0);
    WAITCHUNK(1, t + 1); CHUNK_NB(1);
    WAITCHUNK(2, t + 1); CHUNK_NB(2);
    WAITCHUNK(3, t + 1); CHUNK_NB(3);
    WAITCHUNK(4, t + 1); CHUNK_NB(4);
    WAITCHUNK(5, t + 1); CHUNK_NB(5);
    WAITCHUNK(6, t + 1); CHUNK_NB(6);
    WAITCHUNK(7, t + 1); CHUNK_NB(7);
    __builtin_amdgcn_s_setprio(0);

    // ---- G exchange (G overlays chunks 0-4; fence MFMA LDS reads first) ----
    __syncthreads();                           // (a)
    #pragma unroll
    for (int m = 0; m < 4; m++)
      #pragma unroll
      for (int r4 = 0; r4 < 4; r4++){
        int row = m * 16 + lq * 4 + r4;
        G[q * 2176 + row * 34 + lrow]      = acc[m][0][r4];
        G[q * 2176 + row * 34 + 16 + lrow] = acc[m][1][r4];
      }
    __syncthreads();                           // (b)

    const int base34 = erow * 34 + ec0;
    f32x4 vr = *(const f32x4*)(G + 0 * 2176 + base34) + *(const f32x4*)(G + 4 * 2176 + base34) + bR;
    f32x4 vz = *(const f32x4*)(G + 1 * 2176 + base34) + *(const f32x4*)(G + 5 * 2176 + base34) + bZ;
    f32x4 vi = *(const f32x4*)(G + 2 * 2176 + base34) + *(const f32x4*)(G + 6 * 2176 + base34) + bI;
    f32x4 vh = *(const f32x4*)(G + 3 * 2176 + base34) + *(const f32x4*)(G + 7 * 2176 + base34) + bH;
    __syncthreads();                           // (c) G reads done; ring free

    f32x4 vout; u16x4 hb;
    #pragma unroll
    for (int e = 0; e < 4; e++){
      float rr = 1.f / (1.f + __expf(-vr[e]));
      float zz = 1.f / (1.f + __expf(-vz[e]));
      float x  = vi[e] + rr * vh[e];
      float ex = __expf(-2.f * x);
      float nn = (1.f - ex) / (1.f + ex);
      float hn = nn + zz * (h[e] - nn);
      vout[e] = hn;
      hb[e] = f2bf(hn);
    }
    __hip_atomic_store((unsigned long long*)(Anxt + aaddr),
                       __builtin_bit_cast(unsigned long long, hb),
                       __ATOMIC_RELAXED, __HIP_MEMORY_SCOPE_SYSTEM);
    *(f32x4*)(out + (size_t)grow * 65536 + (size_t)t * 1024 + gcol) = vout;
    h = vout;

    // per-wave drain -> LDS count -> 8th wave releases the block's flag
    asm volatile("s_waitcnt vmcnt(0)" ::: "memory");
    if ((tid & 63) == 0){
      int old = __hip_atomic_fetch_add(&epi_cnt, 1,
                    __ATOMIC_ACQ_REL, __HIP_MEMORY_SCOPE_WORKGROUP);
      if ((old & 7) == 7)
        __hip_atomic_store(&flag[(t * 8 + rb) * 32 + j], 1,
                           __ATOMIC_RELAXED, __HIP_MEMORY_SCOPE_SYSTEM);
    }

    // ---- handoff: poll own 4 producers, stage own chunk of slot t+1 ----
    if (t < 63){
      const int* fp = flag + (t * 8 + rb) * 32 + wv * 4 + (ln & 3);
      for (;;){
        int v = __hip_atomic_load(fp, __ATOMIC_RELAXED, __HIP_MEMORY_SCOPE_SYSTEM);
        if (__all(v != 0)) break;
        __builtin_amdgcn_s_sleep(1);
      }
      STAGE_W(Anxt);
      asm volatile("s_waitcnt vmcnt(0)" ::: "memory");
      __hip_atomic_store(&ready[wv], t + 2, __ATOMIC_RELEASE,
                         __HIP_MEMORY_SCOPE_WORKGROUP);
    }
  }
#undef STAGE_W
#undef CHUNK_NB
#undef WAITCHUNK
}

extern "C" __global__ void __launch_bounds__(512, 1)
gru_seq_rot(char* Arot, const char* WB, const float* bias,
            const float* hidden, float* out, int* flag){
  gru_seq_body<true>(Arot, WB, bias, hidden, out, flag);
}

extern "C" __global__ void __launch_bounds__(512, 1)
gru_seq_pp(char* Arot, const char* WB, const float* bias,
           const float* hidden, float* out, int* flag){
  gru_seq_body<false>(Arot, WB, bias, hidden, out, flag);
}

// ---------------------------------------------------------------------------
extern "C" void kernel_launch(void* const* d_in, const int* in_sizes, int n_in,
                              void* d_out, int out_size, void* d_ws, size_t ws_size,
                              hipStream_t stream){
  const float* hidden = (const float*)d_in[0];
  const float* wih    = (const float*)d_in[1];
  const float* whh    = (const float*)d_in[2];
  const float* bih    = (const float*)d_in[3];
  const float* bhh    = (const float*)d_in[4];
  char*  ws   = (char*)d_ws;
  char*  WB   = ws + WB_OFF;
  float* bias = (float*)(ws + BIAS_OFF);
  int*   flag = (int*)(ws + FLAG_OFF);
  char*  Arot = ws + AROT_OFF;
  float* out  = (float*)d_out;

  hipLaunchKernelGGL(gru_weights, dim3(2048), dim3(256), 0, stream, wih, whh, WB);
  hipLaunchKernelGGL(gru_init,    dim3(256),  dim3(256), 0, stream,
                     hidden, bih, bhh, Arot, bias, flag);
  if (ws_size >= WS_NEED_ROT)
    hipLaunchKernelGGL(gru_seq_rot, dim3(256), dim3(512), 0, stream,
                       Arot, (const char*)WB, (const float*)bias,
                       hidden, out, flag);
  else
    hipLaunchKernelGGL(gru_seq_pp,  dim3(256), dim3(512), 0, stream,
                       Arot, (const char*)WB, (const float*)bias,
                       hidden, out, flag);
}

// Round 17
// 464.505 us; speedup vs baseline: 1.5523x; 1.4809x over previous
//
#include <hip/hip_runtime.h>

// DecoderGRU: h_{t+1} = GRUCell(h_t, h_t), 64 steps. Combined gates: r,z use
// (W_ih+W_hh); n keeps i_n,h_n -> one [512,1024]x[1024,4096] bf16 GEMM + fused
// GRU update per step.
// R17 = R14 (best, 465us) + micro: nontemporal out-stores; flag gated on
// Anext drain only (vmcnt(1)); no handoff work at t=63. Structure unchanged:
// persistent 256 blocks (1/CU), 512 thr = 8 waves (gate x K-half), B in regs
// (AGPR) for the whole sequence, rot A slots through LLC (sc1 producer
// stores), parallel per-producer flags, 8-deep A ring + G overlay, 6
// barriers/step, two-phase vmcnt(12)/vmcnt(0) K-loop.

typedef float  f32x4 __attribute__((ext_vector_type(4)));
typedef __bf16 bf16x8 __attribute__((ext_vector_type(8)));
typedef unsigned short u16x8 __attribute__((ext_vector_type(8)));
typedef unsigned short u16x4 __attribute__((ext_vector_type(4)));

#define GPTR(p) ((const __attribute__((address_space(1))) unsigned int*)(p))
#define LPTR(p) ((__attribute__((address_space(3))) unsigned int*)(p))

// ws layout
#define WB_OFF   0u            // 8 MB frag-packed bf16 weights
#define BIAS_OFF 8388608u      // 16 KB combined biases [4][1024]
#define FLAG_OFF 8404992u      // 64 KB flags [64 t][8 rb][32 j]
#define AROT_OFF 8470528u      // 65 x 1 MB A slots (rot) / 2 x 1 MB (pp)
#define WS_NEED_ROT (8470528ull + 65ull * 1048576ull)

__device__ __forceinline__ unsigned short f2bf(float f){
  unsigned int u = __builtin_bit_cast(unsigned int, f);
  u = (u + 0x7FFFu + ((u >> 16) & 1u)) >> 16;
  return (unsigned short)u;
}

// ---------------------------------------------------------------------------
// B layout: byte = j*262144 + c*32768 + fb*1024 + lane*16 + (k&7)*2,
//   j=col>>5, c=k>>7, fb=(((k>>5)&3)*4+g)*2+((col>>4)&1),
//   lane=(col&15)+((k>>3)&3)*16.  gates: 0=r(+) 1=z(+) 2=i_n(ih) 3=h_n(hh)
// ---------------------------------------------------------------------------
extern "C" __global__ void gru_weights(const float* __restrict__ wih,
                                       const float* __restrict__ whh,
                                       char* __restrict__ WB){
  int gt  = blockIdx.x * 256 + threadIdx.x;   // 524288 threads
  int k0  = (gt & 127) << 3;                  // 8 k's per thread
  int gid = gt >> 7;
  int g   = gid >> 10, colg = gid & 1023;
  int srow = (g < 2) ? g * 1024 + colg : 2048 + colg;
  const float* pa = ((g == 3) ? whh : wih) + srow * 1024 + k0;
  f32x4 v0 = ((const f32x4*)pa)[0];
  f32x4 v1 = ((const f32x4*)pa)[1];
  if (g < 2){
    const float* pb = whh + srow * 1024 + k0;
    v0 += ((const f32x4*)pb)[0];
    v1 += ((const f32x4*)pb)[1];
  }
  u16x8 o;
  #pragma unroll
  for (int e = 0; e < 4; e++){ o[e] = f2bf(v0[e]); o[4 + e] = f2bf(v1[e]); }
  int cck = k0 >> 7;
  int fb  = (((k0 >> 5) & 3) * 4 + g) * 2 + ((colg >> 4) & 1);
  int lane= (colg & 15) + ((k0 >> 3) & 3) * 16;
  int addr= (colg >> 5) * 262144 + cck * 32768 + fb * 1024 + lane * 16;
  *(u16x8*)(WB + addr) = o;
}

// ---------------------------------------------------------------------------
// A layout (64-row slabs): byte = (row>>6)*131072 + (hk>>7)*16384
//   + (((hk>>5)&3)*4 + ((row&63)>>4))*1024
//   + ((row&15)+((hk>>3)&3)*16)*16 + (hk&7)*2
// ---------------------------------------------------------------------------
extern "C" __global__ void gru_init(const float* __restrict__ hidden,
                                    const float* __restrict__ bih,
                                    const float* __restrict__ bhh,
                                    char* __restrict__ A0,
                                    float* __restrict__ bias,
                                    int* __restrict__ flag){
  int gt = blockIdx.x * 256 + threadIdx.x;    // 65536 threads, 8 elems each
  int e0 = gt * 8;
  int r  = e0 >> 10, c0 = e0 & 1023;
  f32x4 v0 = ((const f32x4*)(hidden + e0))[0];
  f32x4 v1 = ((const f32x4*)(hidden + e0))[1];
  u16x8 o;
  #pragma unroll
  for (int e = 0; e < 4; e++){ o[e] = f2bf(v0[e]); o[4 + e] = f2bf(v1[e]); }
  int addr = (r >> 6) * 131072 + (c0 >> 7) * 16384
           + (((c0 >> 5) & 3) * 4 + ((r & 63) >> 4)) * 1024
           + ((r & 15) + ((c0 >> 3) & 3) * 16) * 16;
  *(u16x8*)(A0 + addr) = o;
  if (blockIdx.x < 16){
    int bi = blockIdx.x * 256 + threadIdx.x;  // 4096 bias entries
    int g = bi >> 10, c = bi & 1023;
    float v = (g == 0) ? bih[c]        + bhh[c]
            : (g == 1) ? bih[1024 + c] + bhh[1024 + c]
            : (g == 2) ? bih[2048 + c] : bhh[2048 + c];
    bias[bi] = v;
  }
  if (gt < 16384) flag[gt] = 0;               // 64 KB flag region
}

// ---------------------------------------------------------------------------
// Persistent body. rb=bid&7, j=bid>>3. Wave wv: g=wv&3, kh=wv>>2.
// LDS: A 8-ring (8x16KB); G [8][64][34] f32 overlays @0 after the K-loop.
// Per step (6 barriers): poll+bar -> stage all 8 -> vmcnt(12)+bar ->
// MFMA 0-1 -> vmcnt(0)+bar -> MFMA 2-7 -> bar -> G writes -> bar ->
// GRU + Anext store (first) + nt out store -> vmcnt(1)+bar -> flag store.
// ---------------------------------------------------------------------------
template<bool ROT>
__device__ __forceinline__ void gru_seq_body(
    char* __restrict__ Arot, const char* __restrict__ WB,
    const float* __restrict__ bias, const float* __restrict__ hidden,
    float* __restrict__ out, int* __restrict__ flag)
{
  __shared__ __align__(16) char lds[131072];
  const int tid = threadIdx.x;
  const int wv = tid >> 6, ln = tid & 63;
  const int g = wv & 3, kh = wv >> 2;
  const int lrow = ln & 15, lq = ln >> 4;
  const int bid = blockIdx.x;
  const int rb = bid & 7, j = bid >> 3;
  const int abase = rb * 131072;
  const int bbase = j * 262144;

  // ---- B into registers ONCE for all 64 steps ----
  f32x4 braw[16][2];
  #pragma unroll
  for (int c = 0; c < 8; c++)
    #pragma unroll
    for (int p = 0; p < 2; p++)
      #pragma unroll
      for (int n = 0; n < 2; n++){
        braw[c * 2 + p][n] = *(const f32x4*)(WB + bbase + c * 32768
                               + (((kh * 2 + p) * 4 + g) * 2 + n) * 1024 + ln * 16);
        asm volatile("" : "+v"(braw[c * 2 + p][n]));
      }

  // ---- per-thread epilogue geometry; h and biases in regs ----
  const int erow = tid >> 3, ec0 = (tid & 7) * 4;
  const int grow = rb * 64 + erow, gcol = j * 32 + ec0;
  const f32x4 bR = *(const f32x4*)(bias + gcol);
  const f32x4 bZ = *(const f32x4*)(bias + 1024 + gcol);
  const f32x4 bI = *(const f32x4*)(bias + 2048 + gcol);
  const f32x4 bH = *(const f32x4*)(bias + 3072 + gcol);
  f32x4 h = *(const f32x4*)(hidden + grow * 1024 + gcol);
  const int aaddr = rb * 131072 + (j >> 2) * 16384
                  + ((j & 3) * 4 + (erow >> 4)) * 1024
                  + ((erow & 15) + ((ec0 >> 3) & 3) * 16) * 16 + (ec0 & 7) * 2;
  float* G = (float*)lds;                      // overlays A-ring post-K-loop
  const int q = kh * 4 + g;

#define STAGE_A(bp, cc, AUX) do { \
    _Pragma("unroll") \
    for (int i = 0; i < 2; i++) \
      __builtin_amdgcn_global_load_lds( \
          GPTR((bp) + abase + (cc) * 16384 + tid * 16 + i * 8192), \
          LPTR(lds + (cc) * 16384 + tid * 16 + i * 8192), 16, 0, AUX); \
  } while (0)

// one K-chunk of MFMA, no sync (data already gated resident)
#define CHUNK_NB(c) do { \
    _Pragma("unroll") \
    for (int p = 0; p < 2; p++){ \
      const int ks = kh * 2 + p; \
      bf16x8 a[4]; \
      _Pragma("unroll") \
      for (int m = 0; m < 4; m++) \
        a[m] = *(const bf16x8*)(lds + (c) * 16384 + (ks * 4 + m) * 1024 + ln * 16); \
      _Pragma("unroll") \
      for (int m = 0; m < 4; m++) \
        _Pragma("unroll") \
        for (int n = 0; n < 2; n++) \
          acc[m][n] = __builtin_amdgcn_mfma_f32_16x16x32_bf16( \
              a[m], __builtin_bit_cast(bf16x8, braw[(c) * 2 + p][n]), acc[m][n], 0, 0, 0); \
    } \
  } while (0)

  #pragma unroll 1
  for (int t = 0; t < 64; t++){
    const char* Acur = Arot + (size_t)(ROT ? t : (t & 1)) * 1048576u;
    char* Anxt = Arot + (size_t)(ROT ? (t + 1) : ((t + 1) & 1)) * 1048576u;
    if (t > 0){
      // parallel poll: 32 producer flag words, one per lane (lanes 32-63 dup)
      if (tid < 64){
        const int* fp = flag + ((t - 1) * 8 + rb) * 32 + (tid & 31);
        for (;;){
          int v = __hip_atomic_load(fp, __ATOMIC_RELAXED, __HIP_MEMORY_SCOPE_SYSTEM);
          if (__all(v != 0)) break;
          __builtin_amdgcn_s_sleep(1);
        }
      }
      __syncthreads();   // (1) fences prev G reads vs new staging
    }

    f32x4 acc[4][2];
    #pragma unroll
    for (int m = 0; m < 4; m++)
      #pragma unroll
      for (int n = 0; n < 2; n++) acc[m][n] = f32x4{0.f,0.f,0.f,0.f};

    // issue the entire step's A staging at once (16 loads/thread in flight)
    if constexpr (ROT){
      STAGE_A(Acur, 0, 0); STAGE_A(Acur, 1, 0); STAGE_A(Acur, 2, 0); STAGE_A(Acur, 3, 0);
      STAGE_A(Acur, 4, 0); STAGE_A(Acur, 5, 0); STAGE_A(Acur, 6, 0); STAGE_A(Acur, 7, 0);
    } else {
      STAGE_A(Acur, 0, 17); STAGE_A(Acur, 1, 17); STAGE_A(Acur, 2, 17); STAGE_A(Acur, 3, 17);
      STAGE_A(Acur, 4, 17); STAGE_A(Acur, 5, 17); STAGE_A(Acur, 6, 17); STAGE_A(Acur, 7, 17);
    }

    // phase 1: chunks 0-1 resident -> start MFMA early
    // (a possibly-outstanding nt out-store from step t-1 only delays this
    //  gate by one completion slot; it is ~1us old by now.)
    asm volatile("s_waitcnt vmcnt(12)" ::: "memory");
    __builtin_amdgcn_s_barrier();              // (2)
    __builtin_amdgcn_s_setprio(1);
    CHUNK_NB(0); CHUNK_NB(1);
    __builtin_amdgcn_s_setprio(0);

    // phase 2: everything resident -> uninterrupted MFMA run
    asm volatile("s_waitcnt vmcnt(0)" ::: "memory");
    __builtin_amdgcn_s_barrier();              // (3)
    __builtin_amdgcn_s_setprio(1);
    CHUNK_NB(2); CHUNK_NB(3); CHUNK_NB(4); CHUNK_NB(5); CHUNK_NB(6); CHUNK_NB(7);
    __builtin_amdgcn_s_setprio(0);

    // ---- G exchange overlays A-ring: fence all LDS reads first ----
    __syncthreads();                           // (4)
    #pragma unroll
    for (int m = 0; m < 4; m++)
      #pragma unroll
      for (int r4 = 0; r4 < 4; r4++){
        int row = m * 16 + lq * 4 + r4;
        G[q * 2176 + row * 34 + lrow]      = acc[m][0][r4];
        G[q * 2176 + row * 34 + 16 + lrow] = acc[m][1][r4];
      }
    __syncthreads();                           // (5)

    const int base34 = erow * 34 + ec0;
    f32x4 vr = *(const f32x4*)(G + 0 * 2176 + base34) + *(const f32x4*)(G + 4 * 2176 + base34) + bR;
    f32x4 vz = *(const f32x4*)(G + 1 * 2176 + base34) + *(const f32x4*)(G + 5 * 2176 + base34) + bZ;
    f32x4 vi = *(const f32x4*)(G + 2 * 2176 + base34) + *(const f32x4*)(G + 6 * 2176 + base34) + bI;
    f32x4 vh = *(const f32x4*)(G + 3 * 2176 + base34) + *(const f32x4*)(G + 7 * 2176 + base34) + bH;
    f32x4 vout; u16x4 hb;
    #pragma unroll
    for (int e = 0; e < 4; e++){
      float rr = 1.f / (1.f + __expf(-vr[e]));
      float zz = 1.f / (1.f + __expf(-vz[e]));
      float x  = vi[e] + rr * vh[e];
      float ex = __expf(-2.f * x);
      float nn = (1.f - ex) / (1.f + ex);
      float hn = nn + zz * (h[e] - nn);
      vout[e] = hn;
      hb[e] = f2bf(hn);
    }
    // Anext first (older in vm order, sc1 write-through), then nt out store.
    if (t < 63)
      __hip_atomic_store((unsigned long long*)(Anxt + aaddr),
                         __builtin_bit_cast(unsigned long long, hb),
                         __ATOMIC_RELAXED, __HIP_MEMORY_SCOPE_SYSTEM);
    __builtin_nontemporal_store(vout,
        (f32x4*)(out + (size_t)grow * 65536 + (size_t)t * 1024 + gcol));
    h = vout;

    if (t < 63){
      // retire the Anext store only; the out store drains off-path.
      asm volatile("s_waitcnt vmcnt(1)" ::: "memory");
      __syncthreads();                         // (6)
      if (tid == 0)
        __hip_atomic_store(&flag[(t * 8 + rb) * 32 + j], 1,
                           __ATOMIC_RELAXED, __HIP_MEMORY_SCOPE_SYSTEM);
    }
  }
#undef STAGE_A
#undef CHUNK_NB
}

extern "C" __global__ void __launch_bounds__(512, 1)
gru_seq_rot(char* Arot, const char* WB, const float* bias,
            const float* hidden, float* out, int* flag){
  gru_seq_body<true>(Arot, WB, bias, hidden, out, flag);
}

extern "C" __global__ void __launch_bounds__(512, 1)
gru_seq_pp(char* Arot, const char* WB, const float* bias,
           const float* hidden, float* out, int* flag){
  gru_seq_body<false>(Arot, WB, bias, hidden, out, flag);
}

// ---------------------------------------------------------------------------
extern "C" void kernel_launch(void* const* d_in, const int* in_sizes, int n_in,
                              void* d_out, int out_size, void* d_ws, size_t ws_size,
                              hipStream_t stream){
  const float* hidden = (const float*)d_in[0];
  const float* wih    = (const float*)d_in[1];
  const float* whh    = (const float*)d_in[2];
  const float* bih    = (const float*)d_in[3];
  const float* bhh    = (const float*)d_in[4];
  char*  ws   = (char*)d_ws;
  char*  WB   = ws + WB_OFF;
  float* bias = (float*)(ws + BIAS_OFF);
  int*   flag = (int*)(ws + FLAG_OFF);
  char*  Arot = ws + AROT_OFF;
  float* out  = (float*)d_out;

  hipLaunchKernelGGL(gru_weights, dim3(2048), dim3(256), 0, stream, wih, whh, WB);
  hipLaunchKernelGGL(gru_init,    dim3(256),  dim3(256), 0, stream,
                     hidden, bih, bhh, Arot, bias, flag);
  if (ws_size >= WS_NEED_ROT)
    hipLaunchKernelGGL(gru_seq_rot, dim3(256), dim3(512), 0, stream,
                       Arot, (const char*)WB, (const float*)bias,
                       hidden, out, flag);
  else
    hipLaunchKernelGGL(gru_seq_pp,  dim3(256), dim3(512), 0, stream,
                       Arot, (const char*)WB, (const float*)bias,
                       hidden, out, flag);
}